// Round 12
// baseline (213.856 us; speedup 1.0000x reference)
//
#include <hip/hip_runtime.h>
#include <hip/hip_bf16.h>

#define H 2
#define C 64
#define IN_CH 64
#define HC (H*C)
#define NEG_SLOPE 0.2f
#define NBUCK_MAX 1600
#define NBP_MAX 800   // packed (u16-pair) bucket-counter words
#define SBLK 512      // scatter-role blocks
#define PBLK 2048     // proj-role blocks
#define BKT 32        // nodes per bucket (1563 csragg blocks -> ~6/CU occupancy)
#define CAP 1536      // per-32-node-bucket staging capacity (mean ~1024, +16 sigma)

// ================= K1: fused {scatter role} || {projection role} ===================
// Roles are data-independent and stress different pipes. R11 lesson: LDS is
// allocated per-KERNEL, so the scatter role's arrays throttle proj-role occupancy
// too (19.4KB -> 8 blocks/CU, fused 64->70us). Fix: all scatter counters fit u16
// (chunk hist <= 3125, base/cursor <= CAP=1536), so pack as u16 pairs via the
// atomicAdd(ptr, 1<<16) field trick (no cross-field carry: each field < 65536),
// and overlay bse onto lh in place after reservation. LDS 19.4 -> 6.4KB -> wave cap.
__global__ __launch_bounds__(128) void fused_kernel(
    const float* __restrict__ x, const float* __restrict__ W,
    const float* __restrict__ att_src, const float* __restrict__ att_dst,
    const int* __restrict__ batch, const int* __restrict__ edge,
    __hip_bfloat16* __restrict__ xp, float* __restrict__ asrc,
    float* __restrict__ adst, int* __restrict__ cnt, int* __restrict__ staged,
    int* __restrict__ gbeg, int N, int E, int G, int nbuck) {
    const int t = threadIdx.x;
    if (blockIdx.x < SBLK) {
        // ---------------- scatter role (u16-packed counters) -----------------------
        const int bid = blockIdx.x;
        const int chunkE = (E + SBLK - 1) / SBLK;
        const int nbp = (nbuck + 1) >> 1;
        const int* srcE = edge;
        const int* dstE = edge + E;
        __shared__ int lhp[NBP_MAX], lcurp[NBP_MAX];   // 6.4KB total
        for (int i = t; i < nbp; i += 128) { lhp[i] = 0; lcurp[i] = 0; }
        __syncthreads();
        int beg = bid * chunkE, end = min(beg + chunkE, E);
        for (int i = beg + t; i < end; i += 128) {
            int b = dstE[i] >> 5;
            atomicAdd(&lhp[b >> 1], 1 << ((b & 1) << 4));
        }
        __syncthreads();
        for (int j = t; j < nbp; j += 128) {           // reserve; bse overlays lhp
            int v = lhp[j];
            int lo = atomicAdd(&cnt[2 * j], v & 0xFFFF);
            int hi = atomicAdd(&cnt[2 * j + 1], (v >> 16) & 0xFFFF);
            lhp[j] = lo | (hi << 16);
        }
        __syncthreads();
        for (int i = beg + t; i < end; i += 128) {
            int s = srcE[i], d = dstE[i];              // L2-hot re-read
            int b = d >> 5;
            int sh = (b & 1) << 4;
            int l = (atomicAdd(&lcurp[b >> 1], 1 << sh) >> sh) & 0xFFFF;
            int base = (lhp[b >> 1] >> sh) & 0xFFFF;
            staged[(size_t)b * CAP + base + l] = s | ((d & 31) << 20);  // src < 2^20
        }
        return;
    }
    // ---------------- proj role (R4-proven verbatim; pb in [0, PBLK)) --------------
    int pb = blockIdx.x - SBLK;
    // graph boundary pass over sorted batch: gbeg[g] = first i with batch[i] >= g
    {
        int i = pb * 128 + t;
        if (i < N) {
            int bi = batch[i];
            if (i == 0) {
                for (int g = 0; g <= bi; g++) gbeg[g] = 0;
            } else {
                int bp = batch[i - 1];
                for (int g = bp + 1; g <= bi; g++) gbeg[g] = i;
            }
            if (i == N - 1)
                for (int g = bi + 1; g <= G; g++) gbeg[g] = N;
        }
    }
    float w[64];
    const float4* wr = reinterpret_cast<const float4*>(W + (size_t)t * IN_CH);
#pragma unroll
    for (int q = 0; q < 16; q++) {
        float4 v = wr[q];
        w[4 * q] = v.x; w[4 * q + 1] = v.y; w[4 * q + 2] = v.z; w[4 * q + 3] = v.w;
    }
    float a_s = att_src[t], a_d = att_dst[t];
    int lane = t & 63, head = t >> 6;
    for (int n = pb; n < N; n += PBLK) {
        const float* xr = x + (size_t)n * IN_CH;  // wave-uniform address -> s_load
        float acc = 0.f;
#pragma unroll
        for (int k = 0; k < 64; k++) acc = fmaf(w[k], xr[k], acc);
        xp[(size_t)n * HC + t] = __float2bfloat16(acc);
        float as = acc * a_s, ad = acc * a_d;
#pragma unroll
        for (int d = 32; d > 0; d >>= 1) {
            as += __shfl_xor(as, d, 64);
            ad += __shfl_xor(ad, d, 64);
        }
        if (lane == 0) {
            asrc[(size_t)n * H + head] = as;
            adst[(size_t)n * H + head] = ad;
        }
    }
}

// -------- gather+FMA over NB staged edges: pre-scaled byte offsets, head weight via
// single ds_read at imm offset (swl already +hsel). All loads before FMAs (MLP).
template<int NB>
__device__ __forceinline__ void gfma(const char* __restrict__ xb,
                                     const int* __restrict__ si,
                                     const float* __restrict__ swl,
                                     uint laneoff, float& accx, float& accy) {
    uint bu[NB];
#pragma unroll
    for (int j = 0; j < NB; j++) {
        uint boff = (uint)si[j] + laneoff;           // src*256 + lane*4
        bu[j] = *reinterpret_cast<const uint*>(xb + boff);
    }
#pragma unroll
    for (int j = 0; j < NB; j++) {
        float w = swl[2 * j];                        // swf[2*j + hsel]
        accx = fmaf(w, __uint_as_float(bu[j] << 16), accx);
        accy = fmaf(w, __uint_as_float(bu[j] & 0xffff0000u), accy);
    }
}

// ================= K2: fused CSR-build (in LDS) + softmax + aggregation ============
// R11-proven verbatim. One block per 32-node bucket (1563 blocks): local hist ->
// 32-wide scan -> LDS csr scatter -> register-accumulation wave-per-node
// aggregation (8 nodes/wave). (256,6): ~6 blocks/CU; VGPR 44 << 85 cap, no spill.
// Register accumulation only: LDS-atomic ACCUMULATION measured ~serial (R5: 1404us).
__global__ __launch_bounds__(256, 6) void csragg_kernel(
    const __hip_bfloat16* __restrict__ xp, const float* __restrict__ asrc,
    const float* __restrict__ adst, const int* __restrict__ cnt,
    const int* __restrict__ staged_all, const float* __restrict__ bias,
    float* __restrict__ out, int N) {
    __shared__ int lcsr[CAP];        // 6KB: per-node-grouped pre-scaled byte offsets
    __shared__ int loff[BKT + 1];
    __shared__ int lh[BKT], cur[BKT];
    __shared__ int sidx[4][32];
    __shared__ float swf[4][64];
    int b = blockIdx.x, tid = threadIdx.x;
    int lane = tid & 63, wid = tid >> 6;
    int size = cnt[b];
    const int* st = staged_all + (size_t)b * CAP;
    if (tid < BKT) lh[tid] = 0;
    __syncthreads();
    for (int i = tid; i < size; i += 256)
        atomicAdd(&lh[st[i] >> 20], 1);
    __syncthreads();
    if (wid == 0 && lane < BKT) {    // 32-wide exclusive scan in half a wave
        int v = lh[lane];
        int inc = v;
#pragma unroll
        for (int d = 1; d < BKT; d <<= 1) {
            int u = __shfl_up(inc, d, 64);
            if (lane >= d) inc += u;
        }
        loff[lane] = inc - v;
        cur[lane] = inc - v;
        if (lane == BKT - 1) loff[BKT] = inc;
    }
    __syncthreads();
    for (int i = tid; i < size; i += 256) {
        int e = st[i];
        int pos = atomicAdd(&cur[e >> 20], 1);
        lcsr[pos] = (e & 0xFFFFF) << 8;   // pre-scaled xp-row byte offset
    }
    __syncthreads();
    // ---- aggregation (head-split lanes: 0-31 head 0, 32-63 head 1) ----
    const uint* xpw = reinterpret_cast<const uint*>(xp);
    const char* xb = reinterpret_cast<const char*>(xp);
    int cl = lane & 31, hsel = lane >> 5;
    uint laneoff = (uint)lane * 4u;
    int* si = sidx[wid];
    float* swl = swf[wid] + hsel;
    for (int k = 0; k < 8; k++) {
        int nd = wid * 8 + k;
        int n = b * BKT + nd;
        if (n >= N) break;
        int o0 = loff[nd];
        int deg = loff[nd + 1] - o0;     // real edges only (self-loop analytic)
        float adh = adst[2 * n + hsel];
        float es = asrc[2 * n + hsel] + adh;
        es = (es > 0.f) ? es : NEG_SLOPE * es;
        float wself = __expf(es);
        float ssum = (cl == 0) ? wself : 0.f;  // self-loop in denominator once/head
        uint u = xpw[(size_t)n * 64 + lane];
        float accx = wself * __uint_as_float(u << 16);
        float accy = wself * __uint_as_float(u & 0xffff0000u);
        for (int base = 0; base < deg; base += 32) {
            int i = base + cl;
            int boff = 0;
            float w = 0.f;
            if (i < deg) {
                boff = lcsr[o0 + i];     // both halves same addr -> 2-way = free
                float t = asrc[(boff >> 7) + hsel] + adh;  // 2*src == boff>>7
                t = (t > 0.f) ? t : NEG_SLOPE * t;
                w = __expf(t);
            }
            ssum += w;
            if (!hsel) si[cl] = boff;    // one writer per slot
            swl[2 * cl] = w;             // swf[2*cl + hsel]; 2-way alias = free
            int nb = min(deg - base, 32);
            if (nb > 16) gfma<32>(xb, si, swl, laneoff, accx, accy);
            else         gfma<16>(xb, si, swl, laneoff, accx, accy);
        }
#pragma unroll
        for (int d = 16; d > 0; d >>= 1) ssum += __shfl_xor(ssum, d, 64);
        float inv = 1.f / ssum;
        accx *= inv;
        accy *= inv;
        float ox = 0.5f * (accx + __shfl_xor(accx, 32, 64));
        float oy = 0.5f * (accy + __shfl_xor(accy, 32, 64));
        if (lane < 32) {
            float vx = ox + bias[2 * cl];
            float vy = oy + bias[2 * cl + 1];
            *reinterpret_cast<float2*>(out + (size_t)n * C + 2 * cl) =
                make_float2(vx, vy);
        }
    }
}

// ================= K3: pool = segment mean via precomputed bounds, 4 row-streams ====
__global__ __launch_bounds__(256) void pool_kernel(const float* __restrict__ hn,
                                                   const int* __restrict__ gbeg,
                                                   float* __restrict__ outG, int G) {
    int g = blockIdx.x;
    int c = threadIdx.x & 63, r = threadIdx.x >> 6;  // 4 parallel row streams
    int beg = gbeg[g], end = gbeg[g + 1];
    float s = 0.f;
    for (int n = beg + r; n < end; n += 4) s += hn[(size_t)n * C + c];
    __shared__ float red[256];
    red[threadIdx.x] = s;
    __syncthreads();
    if (r == 0) {
        float tot = red[c] + red[64 + c] + red[128 + c] + red[192 + c];
        outG[(size_t)g * C + c] = tot / fmaxf((float)(end - beg), 1.f);
    }
}

extern "C" void kernel_launch(void* const* d_in, const int* in_sizes, int n_in,
                              void* d_out, int out_size, void* d_ws, size_t ws_size,
                              hipStream_t stream) {
    const float* x       = (const float*)d_in[0];
    const int*   edge    = (const int*)d_in[1];
    const int*   batch   = (const int*)d_in[2];
    const float* W       = (const float*)d_in[3];
    const float* att_src = (const float*)d_in[4];
    const float* att_dst = (const float*)d_in[5];
    const float* bias    = (const float*)d_in[6];

    int N = in_sizes[0] / IN_CH;
    int E = in_sizes[1] / 2;
    int G = out_size / C - N;
    int nbuck = (N + BKT - 1) / BKT;       // 1563 for N=50000 (must be <= NBUCK_MAX)
    int nbuck_pad = ((nbuck + 1) >> 1) << 1;  // even: reservation touches cnt[2j+1]

    char* p = (char*)d_ws;
    auto alloc = [&](size_t bytes) {
        char* r = p;
        p += (bytes + 255) & ~(size_t)255;
        return r;
    };
    __hip_bfloat16* xp = (__hip_bfloat16*)alloc((size_t)N * HC * 2);
    float* asrc    = (float*)alloc((size_t)N * H * 4);
    float* adst    = (float*)alloc((size_t)N * H * 4);
    int*   cnt     = (int*)alloc((size_t)nbuck_pad * 4);
    int*   staged  = (int*)alloc((size_t)nbuck * CAP * 4);
    int*   gbeg    = (int*)alloc((size_t)(G + 1) * 4);

    hipMemsetAsync(cnt, 0, (size_t)nbuck_pad * 4, stream);
    fused_kernel<<<SBLK + PBLK, 128, 0, stream>>>(x, W, att_src, att_dst, batch, edge,
                                                  xp, asrc, adst, cnt, staged, gbeg,
                                                  N, E, G, nbuck);
    csragg_kernel<<<nbuck, 256, 0, stream>>>(xp, asrc, adst, cnt, staged, bias,
                                             (float*)d_out, N);
    pool_kernel<<<G, 256, 0, stream>>>((const float*)d_out, gbeg,
                                       (float*)d_out + (size_t)N * C, G);
}

// Round 13
// 187.923 us; speedup vs baseline: 1.1380x; 1.1380x over previous
//
#include <hip/hip_runtime.h>
#include <hip/hip_bf16.h>

#define H 2
#define C 64
#define IN_CH 64
#define HC (H*C)
#define NEG_SLOPE 0.2f
#define NBUCK_MAX 1024
#define SBLK 512      // scatter-role blocks
#define PBLK 2048     // proj-role blocks
#define BKT 64        // nodes per bucket
#define CAP 3072      // per-64-node-bucket staging capacity (mean ~2048, sigma ~45)

// ================= K1: fused {scatter role} || {projection role} ===================
// R9-verified best (192.3us total). Roles are data-independent and stress different
// pipes (LDS-atomic/memory vs VALU-FMA); cnt zeroed by prior hipMemsetAsync.
// Post-R12 knowledge: fused is CONTENTION-bound, not occupancy-bound -- LDS 19.4KB
// (R11, occ 28%) = 70us, LDS 6.6KB packed (R12, occ 40%) = 78us, this 12.3KB
// (occ 39%) = 64.3us. Unpacked counters + BKT=64 is the measured optimum.
__global__ __launch_bounds__(128) void fused_kernel(
    const float* __restrict__ x, const float* __restrict__ W,
    const float* __restrict__ att_src, const float* __restrict__ att_dst,
    const int* __restrict__ batch, const int* __restrict__ edge,
    __hip_bfloat16* __restrict__ xp, float* __restrict__ asrc,
    float* __restrict__ adst, int* __restrict__ cnt, int* __restrict__ staged,
    int* __restrict__ gbeg, int N, int E, int G, int nbuck) {
    const int t = threadIdx.x;
    if (blockIdx.x < SBLK) {
        // ---------------- scatter role (R4/R7-proven, 128-thread strides) ----------
        const int bid = blockIdx.x;
        const int chunkE = (E + SBLK - 1) / SBLK;
        const int* srcE = edge;
        const int* dstE = edge + E;
        __shared__ int lh[NBUCK_MAX], bse[NBUCK_MAX], lcur[NBUCK_MAX];
        for (int i = t; i < nbuck; i += 128) { lh[i] = 0; lcur[i] = 0; }
        __syncthreads();
        int beg = bid * chunkE, end = min(beg + chunkE, E);
        for (int i = beg + t; i < end; i += 128)
            atomicAdd(&lh[dstE[i] >> 6], 1);
        __syncthreads();
        for (int i = t; i < nbuck; i += 128)
            bse[i] = atomicAdd(&cnt[i], lh[i]);  // reserve [bse, bse+lh)
        __syncthreads();
        for (int i = beg + t; i < end; i += 128) {
            int s = srcE[i], d = dstE[i];        // L2-hot re-read
            int b = d >> 6;
            int l = atomicAdd(&lcur[b], 1);
            staged[(size_t)b * CAP + bse[b] + l] = s | ((d & 63) << 20);  // src < 2^20
        }
        return;
    }
    // ---------------- proj role (R4-proven verbatim; pb in [0, PBLK)) --------------
    int pb = blockIdx.x - SBLK;
    // graph boundary pass over sorted batch: gbeg[g] = first i with batch[i] >= g
    {
        int i = pb * 128 + t;
        if (i < N) {
            int bi = batch[i];
            if (i == 0) {
                for (int g = 0; g <= bi; g++) gbeg[g] = 0;
            } else {
                int bp = batch[i - 1];
                for (int g = bp + 1; g <= bi; g++) gbeg[g] = i;
            }
            if (i == N - 1)
                for (int g = bi + 1; g <= G; g++) gbeg[g] = N;
        }
    }
    float w[64];
    const float4* wr = reinterpret_cast<const float4*>(W + (size_t)t * IN_CH);
#pragma unroll
    for (int q = 0; q < 16; q++) {
        float4 v = wr[q];
        w[4 * q] = v.x; w[4 * q + 1] = v.y; w[4 * q + 2] = v.z; w[4 * q + 3] = v.w;
    }
    float a_s = att_src[t], a_d = att_dst[t];
    int lane = t & 63, head = t >> 6;
    for (int n = pb; n < N; n += PBLK) {
        const float* xr = x + (size_t)n * IN_CH;  // wave-uniform address -> s_load
        float acc = 0.f;
#pragma unroll
        for (int k = 0; k < 64; k++) acc = fmaf(w[k], xr[k], acc);
        xp[(size_t)n * HC + t] = __float2bfloat16(acc);
        float as = acc * a_s, ad = acc * a_d;
#pragma unroll
        for (int d = 32; d > 0; d >>= 1) {
            as += __shfl_xor(as, d, 64);
            ad += __shfl_xor(ad, d, 64);
        }
        if (lane == 0) {
            asrc[(size_t)n * H + head] = as;
            adst[(size_t)n * H + head] = ad;
        }
    }
}

// -------- gather+FMA over NB staged edges: pre-scaled byte offsets, head weight via
// single ds_read at imm offset (swl already +hsel). All loads before FMAs (MLP).
template<int NB>
__device__ __forceinline__ void gfma(const char* __restrict__ xb,
                                     const int* __restrict__ si,
                                     const float* __restrict__ swl,
                                     uint laneoff, float& accx, float& accy) {
    uint bu[NB];
#pragma unroll
    for (int j = 0; j < NB; j++) {
        uint boff = (uint)si[j] + laneoff;           // src*256 + lane*4
        bu[j] = *reinterpret_cast<const uint*>(xb + boff);
    }
#pragma unroll
    for (int j = 0; j < NB; j++) {
        float w = swl[2 * j];                        // swf[2*j + hsel]
        accx = fmaf(w, __uint_as_float(bu[j] << 16), accx);
        accy = fmaf(w, __uint_as_float(bu[j] & 0xffff0000u), accy);
    }
}

// ================= K2: fused CSR-build (in LDS) + softmax + aggregation ============
// R7/R9-proven verbatim. One block per 64-node bucket: local hist (1 LDS atomic/
// edge) -> 64-wide wave scan -> LDS csr scatter (1 LDS atomic/edge) -> proven
// register-accumulation wave-per-node aggregation (16 nodes/wave).
// At 27% occupancy this runs the gather path at ~2.75-3.4 TB/s L2-miss BW = its
// measured floor (xp 12.8MB >> 4MB per-XCD L2, uniform-random src -> no locality).
// Register accumulation only: LDS-atomic ACCUMULATION measured ~serial (R5: 1404us).
// (256,4): (256,8) caps VGPR at 32 -> scratch spill (R2: +50MB writes, +12us).
__global__ __launch_bounds__(256, 4) void csragg_kernel(
    const __hip_bfloat16* __restrict__ xp, const float* __restrict__ asrc,
    const float* __restrict__ adst, const int* __restrict__ cnt,
    const int* __restrict__ staged_all, const float* __restrict__ bias,
    float* __restrict__ out, int N) {
    __shared__ int lcsr[CAP];        // 12KB: per-node-grouped pre-scaled byte offsets
    __shared__ int loff[BKT + 1];
    __shared__ int lh[BKT], cur[BKT];
    __shared__ int sidx[4][32];
    __shared__ float swf[4][64];
    int b = blockIdx.x, tid = threadIdx.x;
    int lane = tid & 63, wid = tid >> 6;
    int size = cnt[b];
    const int* st = staged_all + (size_t)b * CAP;
    if (tid < BKT) lh[tid] = 0;
    __syncthreads();
    for (int i = tid; i < size; i += 256)
        atomicAdd(&lh[st[i] >> 20], 1);
    __syncthreads();
    if (wid == 0) {                  // 64-wide exclusive scan in one wave
        int v = lh[lane];
        int inc = v;
#pragma unroll
        for (int d = 1; d < 64; d <<= 1) {
            int u = __shfl_up(inc, d, 64);
            if (lane >= d) inc += u;
        }
        loff[lane] = inc - v;
        cur[lane] = inc - v;
        if (lane == 63) loff[BKT] = inc;
    }
    __syncthreads();
    for (int i = tid; i < size; i += 256) {
        int e = st[i];
        int pos = atomicAdd(&cur[e >> 20], 1);
        lcsr[pos] = (e & 0xFFFFF) << 8;   // pre-scaled xp-row byte offset
    }
    __syncthreads();
    // ---- aggregation (head-split lanes: 0-31 head 0, 32-63 head 1) ----
    const uint* xpw = reinterpret_cast<const uint*>(xp);
    const char* xb = reinterpret_cast<const char*>(xp);
    int cl = lane & 31, hsel = lane >> 5;
    uint laneoff = (uint)lane * 4u;
    int* si = sidx[wid];
    float* swl = swf[wid] + hsel;
    for (int k = 0; k < 16; k++) {
        int nd = wid * 16 + k;
        int n = b * BKT + nd;
        if (n >= N) break;
        int o0 = loff[nd];
        int deg = loff[nd + 1] - o0;     // real edges only (self-loop analytic)
        float adh = adst[2 * n + hsel];
        float es = asrc[2 * n + hsel] + adh;
        es = (es > 0.f) ? es : NEG_SLOPE * es;
        float wself = __expf(es);
        float ssum = (cl == 0) ? wself : 0.f;  // self-loop in denominator once/head
        uint u = xpw[(size_t)n * 64 + lane];
        float accx = wself * __uint_as_float(u << 16);
        float accy = wself * __uint_as_float(u & 0xffff0000u);
        for (int base = 0; base < deg; base += 32) {
            int i = base + cl;
            int boff = 0;
            float w = 0.f;
            if (i < deg) {
                boff = lcsr[o0 + i];     // both halves same addr -> 2-way = free
                float t = asrc[(boff >> 7) + hsel] + adh;  // 2*src == boff>>7
                t = (t > 0.f) ? t : NEG_SLOPE * t;
                w = __expf(t);
            }
            ssum += w;
            if (!hsel) si[cl] = boff;    // one writer per slot
            swl[2 * cl] = w;             // swf[2*cl + hsel]; 2-way alias = free
            int nb = min(deg - base, 32);
            if (nb > 16) gfma<32>(xb, si, swl, laneoff, accx, accy);
            else         gfma<16>(xb, si, swl, laneoff, accx, accy);
        }
#pragma unroll
        for (int d = 16; d > 0; d >>= 1) ssum += __shfl_xor(ssum, d, 64);
        float inv = 1.f / ssum;
        accx *= inv;
        accy *= inv;
        float ox = 0.5f * (accx + __shfl_xor(accx, 32, 64));
        float oy = 0.5f * (accy + __shfl_xor(accy, 32, 64));
        if (lane < 32) {
            float vx = ox + bias[2 * cl];
            float vy = oy + bias[2 * cl + 1];
            *reinterpret_cast<float2*>(out + (size_t)n * C + 2 * cl) =
                make_float2(vx, vy);
        }
    }
}

// ================= K3: pool = segment mean via precomputed bounds, 4 row-streams ====
__global__ __launch_bounds__(256) void pool_kernel(const float* __restrict__ hn,
                                                   const int* __restrict__ gbeg,
                                                   float* __restrict__ outG, int G) {
    int g = blockIdx.x;
    int c = threadIdx.x & 63, r = threadIdx.x >> 6;  // 4 parallel row streams
    int beg = gbeg[g], end = gbeg[g + 1];
    float s = 0.f;
    for (int n = beg + r; n < end; n += 4) s += hn[(size_t)n * C + c];
    __shared__ float red[256];
    red[threadIdx.x] = s;
    __syncthreads();
    if (r == 0) {
        float tot = red[c] + red[64 + c] + red[128 + c] + red[192 + c];
        outG[(size_t)g * C + c] = tot / fmaxf((float)(end - beg), 1.f);
    }
}

extern "C" void kernel_launch(void* const* d_in, const int* in_sizes, int n_in,
                              void* d_out, int out_size, void* d_ws, size_t ws_size,
                              hipStream_t stream) {
    const float* x       = (const float*)d_in[0];
    const int*   edge    = (const int*)d_in[1];
    const int*   batch   = (const int*)d_in[2];
    const float* W       = (const float*)d_in[3];
    const float* att_src = (const float*)d_in[4];
    const float* att_dst = (const float*)d_in[5];
    const float* bias    = (const float*)d_in[6];

    int N = in_sizes[0] / IN_CH;
    int E = in_sizes[1] / 2;
    int G = out_size / C - N;
    int nbuck = (N + BKT - 1) / BKT;       // 782 for N=50000 (must be <= NBUCK_MAX)

    char* p = (char*)d_ws;
    auto alloc = [&](size_t bytes) {
        char* r = p;
        p += (bytes + 255) & ~(size_t)255;
        return r;
    };
    __hip_bfloat16* xp = (__hip_bfloat16*)alloc((size_t)N * HC * 2);
    float* asrc    = (float*)alloc((size_t)N * H * 4);
    float* adst    = (float*)alloc((size_t)N * H * 4);
    int*   cnt     = (int*)alloc((size_t)nbuck * 4);
    int*   staged  = (int*)alloc((size_t)nbuck * CAP * 4);
    int*   gbeg    = (int*)alloc((size_t)(G + 1) * 4);

    hipMemsetAsync(cnt, 0, (size_t)nbuck * 4, stream);
    fused_kernel<<<SBLK + PBLK, 128, 0, stream>>>(x, W, att_src, att_dst, batch, edge,
                                                  xp, asrc, adst, cnt, staged, gbeg,
                                                  N, E, G, nbuck);
    csragg_kernel<<<nbuck, 256, 0, stream>>>(xp, asrc, adst, cnt, staged, bias,
                                             (float*)d_out, N);
    pool_kernel<<<G, 256, 0, stream>>>((const float*)d_out, gbeg,
                                       (float*)d_out + (size_t)N * C, G);
}